// Round 6
// baseline (333.872 us; speedup 1.0000x reference)
//
#include <hip/hip_runtime.h>
#include <hip/hip_bf16.h>

// PatchLoss v3 for MI355X (gfx950) — phase-decoupled 3-kernel design.
//
// loss = (1/(B*T^2)) * sum_{b,t,u} w[b,t,u] * (z2[b,t] + z2[b,u] - 2*G[b,t,u])
//   w = exp(-sum_k gt_dT^2/(2 sigma_k^2)),  G[b] = z_b z_b^T,  z2 = ||z_bt||^2
//
// History: r1 fused 117us, r5 fused-2blk 124us — both latency-bound with all
// pipes idle (Mfma ~5, VALU ~14, HBM ~17%, Occ ~40). Root cause: per-block
// serial critical path (24 barrier slabs; phase-2 vmcnt drain per iter, only
// 4 loads in flight). This round:
//   K1 gram: BK=64 (12 barriers), issue-loads-early/ds_write-late, ZPAD=72
//            (conflict-free), 512 blocks x 8 waves -> G(39MB)+z2 to ws.
//   K2 loss: 2048 blocks x 256 thr (8 blk/CU, 32 waves, NO barriers),
//            grid-stride unroll-4 => 12 loads in flight per lane.
//   K3 finalize: single block, plain write (no atomic, no memset dispatch).
// Fallback: r5 fused kernel if ws_size < ~39.6 MB.

typedef __attribute__((ext_vector_type(8))) __bf16 bf16x8;
typedef __attribute__((ext_vector_type(4))) float f32x4;

#define NB   256
#define TT   196
#define DD   768
#define TTT  (TT * TT)          // 38416
#define BK2  64
#define NSLAB (DD / BK2)        // 12
#define ZPAD 72                 // 144B row stride = 36 banks (== 4 mod 32): spread

__device__ __forceinline__ bf16x8 pack8(const float4& a, const float4& b) {
    bf16x8 v;
    v[0] = (__bf16)a.x; v[1] = (__bf16)a.y; v[2] = (__bf16)a.z; v[3] = (__bf16)a.w;
    v[4] = (__bf16)b.x; v[5] = (__bf16)b.y; v[6] = (__bf16)b.z; v[7] = (__bf16)b.w;
    return v;
}
__device__ __forceinline__ float sq8(const float4& a, const float4& b) {
    return a.x*a.x + a.y*a.y + a.z*a.z + a.w*a.w
         + b.x*b.x + b.y*b.y + b.z*b.z + b.w*b.w;
}

// ---------------- K1: gram ----------------
// grid 512 = (b, s): s=0 -> t rows [0,112) (7 MFMA waves), s=1 -> [112,208)
// (6 MFMA waves, rows >=196 are zero pads). 512 threads.
// Staging per slab (64 cols): thread covers cols (tid&7)*8..+7 of rows
// r0, r0+64, r0+128 (+192 if r0<16), r0 = tid>>3.

__global__ __launch_bounds__(512, 4)
void gram_k(const float* __restrict__ z,
            float* __restrict__ G,
            float* __restrict__ z2g)
{
    __shared__ __bf16 Zt[2][208][ZPAD];     // 58.5 KB

    const int hw = blockIdx.x;              // XCD swizzle, 512%8==0 bijective
    const int lb = (hw & 7) * 64 + (hw >> 3);
    const int b  = lb >> 1;
    const int s  = lb & 1;
    const int nmf = 7 - s;

    const int tid  = threadIdx.x;
    const int lane = tid & 63;
    const int wid  = tid >> 6;

    const int r0   = tid >> 3;              // 0..63
    const int scol = (tid & 7) << 3;        // 0..56 step 8
    const bool seg3 = (r0 < 16);            // rows 192..207 exist
    const int rows[4] = { r0, r0 + 64, r0 + 128, r0 + 192 };
    const float* zb = z + (size_t)b * TT * DD + scol;

    f32x4 acc[13];
#pragma unroll
    for (int j = 0; j < 13; ++j) acc[j] = (f32x4){0.f, 0.f, 0.f, 0.f};
    float z2p[4] = {0.f, 0.f, 0.f, 0.f};

    // prologue: stage slab 0
#pragma unroll
    for (int g = 0; g < 4; ++g) {
        if (g == 3 && !seg3) continue;
        const int  row = rows[g];
        const bool v   = row < TT;
        float4 a0 = make_float4(0.f,0.f,0.f,0.f), a1 = a0;
        if (v) {
            const float* p = zb + (size_t)row * DD;
            a0 = *(const float4*)(p);
            a1 = *(const float4*)(p + 4);
        }
        z2p[g] += sq8(a0, a1);
        *(bf16x8*)&Zt[0][row][scol] = pack8(a0, a1);
    }

    const int arow = (s * 112 + (wid << 4) + (lane & 15)) % 208;  // wid>=nmf: dummy
    const int koff = (lane >> 4) << 3;

    int cur = 0;
#pragma unroll 1
    for (int ks = 0; ks < NSLAB; ++ks) {
        __syncthreads();
        const bool more = (ks + 1) < NSLAB;

        // 1) issue next-slab loads FIRST (latency hides under MFMA below)
        float4 L0[4], L1[4];
#pragma unroll
        for (int g = 0; g < 4; ++g) {
            L0[g] = make_float4(0.f,0.f,0.f,0.f); L1[g] = L0[g];
            if (more && !(g == 3 && !seg3) && rows[g] < TT) {
                const float* p = zb + (size_t)rows[g] * DD + (ks + 1) * BK2;
                L0[g] = *(const float4*)(p);
                L1[g] = *(const float4*)(p + 4);
            }
        }

        // 2) MFMA on current slab (two K=32 halves)
        if (wid < nmf) {
            bf16x8 af0 = *(const bf16x8*)&Zt[cur][arow][koff];
            bf16x8 af1 = *(const bf16x8*)&Zt[cur][arow][32 + koff];
#pragma unroll
            for (int j = 0; j < 13; ++j) {
                bf16x8 b0 = *(const bf16x8*)&Zt[cur][(j << 4) + (lane & 15)][koff];
                acc[j] = __builtin_amdgcn_mfma_f32_16x16x32_bf16(af0, b0, acc[j], 0, 0, 0);
            }
#pragma unroll
            for (int j = 0; j < 13; ++j) {
                bf16x8 b1 = *(const bf16x8*)&Zt[cur][(j << 4) + (lane & 15)][32 + koff];
                acc[j] = __builtin_amdgcn_mfma_f32_16x16x32_bf16(af1, b1, acc[j], 0, 0, 0);
            }
        }

        // 3) commit staged data to the other buffer
        if (more) {
#pragma unroll
            for (int g = 0; g < 4; ++g) {
                if (g == 3 && !seg3) continue;
                z2p[g] += sq8(L0[g], L1[g]);
                *(bf16x8*)&Zt[cur ^ 1][rows[g]][scol] = pack8(L0[g], L1[g]);
            }
        }
        cur ^= 1;
    }

    // z2: reduce over the 8 threads sharing each row (lanes differ in low 3 bits)
    if (s == 0) {
#pragma unroll
        for (int g = 0; g < 4; ++g) {
            if (g == 3 && !seg3) continue;
            float v = z2p[g];
            v += __shfl_xor(v, 1); v += __shfl_xor(v, 2); v += __shfl_xor(v, 4);
            if ((tid & 7) == 0 && rows[g] < TT) z2g[b * TT + rows[g]] = v;
        }
    }

    // store G (C/D layout: col u = lane&15, row t-offset = (lane>>4)*4 + r)
    if (wid < nmf) {
        const int l15 = lane & 15;
        const int lq  = lane >> 4;
#pragma unroll
        for (int j = 0; j < 13; ++j) {
            const int u = (j << 4) + l15;
            if (u >= TT) continue;
#pragma unroll
            for (int r = 0; r < 4; ++r) {
                const int t = s * 112 + (wid << 4) + (lq << 2) + r;
                if (t < TT) G[((size_t)b * TT + t) * TT + u] = acc[j][r];
            }
        }
    }
}

// ---------------- K2: loss stream ----------------

#define BTH   256
#define BGRID 2048

__global__ __launch_bounds__(BTH, 8)
void loss_k(const float4* __restrict__ gt4,
            const float* __restrict__ G,
            const float* __restrict__ z2g,
            const float* __restrict__ sigma,
            float* __restrict__ partials)
{
    const int tid = threadIdx.x;
    const float4 sg = *(const float4*)sigma;
    const float c0 = 0.5f / (sg.x * sg.x);
    const float c1 = 0.5f / (sg.y * sg.y);
    const float c2 = 0.5f / (sg.z * sg.z);
    const float c3 = 0.5f / (sg.w * sg.w);

    const unsigned total = NB * TTT;            // 9,834,496
    const unsigned S     = BTH * BGRID;         // 524,288
    unsigned q = blockIdx.x * BTH + tid;
    float lsum = 0.f;

    // main: unroll-4, 12 independent loads in flight per lane
#pragma unroll 1
    while (q + 3 * S < total) {
        unsigned qs[4];
        float4 g[4]; float Gv[4], zt[4], zu[4];
#pragma unroll
        for (int k = 0; k < 4; ++k) qs[k] = q + k * S;
#pragma unroll
        for (int k = 0; k < 4; ++k) {
            const unsigned b  = qs[k] / TTT;
            const unsigned rr = qs[k] - b * TTT;
            const unsigned t  = rr / TT;
            const unsigned u  = rr - t * TT;
            g[k]  = gt4[qs[k]];
            Gv[k] = G[qs[k]];
            zt[k] = z2g[b * TT + t];
            zu[k] = z2g[b * TT + u];
        }
#pragma unroll
        for (int k = 0; k < 4; ++k) {
            const float sS = g[k].x*g[k].x*c0 + g[k].y*g[k].y*c1
                           + g[k].z*g[k].z*c2 + g[k].w*g[k].w*c3;
            lsum += __expf(-sS) * (zt[k] + zu[k] - 2.f * Gv[k]);
        }
        q += 4 * S;
    }
    // tail
#pragma unroll 1
    while (q < total) {
        const unsigned b  = q / TTT;
        const unsigned rr = q - b * TTT;
        const unsigned t  = rr / TT;
        const unsigned u  = rr - t * TT;
        const float4 g = gt4[q];
        const float sS = g.x*g.x*c0 + g.y*g.y*c1 + g.z*g.z*c2 + g.w*g.w*c3;
        lsum += __expf(-sS) * (z2g[b * TT + t] + z2g[b * TT + u] - 2.f * G[q]);
        q += S;
    }

#pragma unroll
    for (int off = 32; off > 0; off >>= 1) lsum += __shfl_xor(lsum, off);
    __shared__ float red[BTH / 64];
    if ((tid & 63) == 0) red[tid >> 6] = lsum;
    __syncthreads();
    if (tid == 0) {
        float t = 0.f;
#pragma unroll
        for (int w = 0; w < BTH / 64; ++w) t += red[w];
        partials[blockIdx.x] = t;
    }
}

// ---------------- K3: finalize ----------------

__global__ __launch_bounds__(256)
void final_k(const float* __restrict__ partials, float* __restrict__ out)
{
    const int tid = threadIdx.x;
    float s = 0.f;
#pragma unroll
    for (int k = 0; k < BGRID / 256; ++k) s += partials[tid + k * 256];
#pragma unroll
    for (int off = 32; off > 0; off >>= 1) s += __shfl_xor(s, off);
    __shared__ float red[4];
    if ((tid & 63) == 0) red[tid >> 6] = s;
    __syncthreads();
    if (tid == 0)
        out[0] = (red[0] + red[1] + red[2] + red[3])
               * (1.0f / ((float)NB * (float)TT * (float)TT));
}

// ---------------- Fallback: r5 fused (ws too small) ----------------

#define BK 32
#define NKS (DD / BK)
#define ZP2 40
#define NTH 512

__global__ __launch_bounds__(NTH)
void patch_loss_fused2(const float* __restrict__ z,
                       const float* __restrict__ gt,
                       const float* __restrict__ sigma,
                       float* __restrict__ out)
{
    __shared__ __bf16 Zt[2][208][ZP2];
    __shared__ float z2s[208];
    __shared__ float red[8];

    const int hw = blockIdx.x;
    const int lb = (hw & 7) * 64 + (hw >> 3);
    const int b  = lb >> 1;
    const int s  = lb & 1;
    const int nmf = 7 - s;

    const int tid  = threadIdx.x;
    const int lane = tid & 63;
    const int wid  = tid >> 6;

    const int  srow = tid >> 2;
    const int  scol = (tid & 3) << 3;
    const int  row1 = srow + 128;
    const bool r1st = row1 < 208;
    const bool r1v  = row1 < TT;
    const float* zp0 = z + ((size_t)b * TT + srow) * DD + scol;
    const float* zp1 = z + ((size_t)b * TT + row1) * DD + scol;

    f32x4 acc[13];
#pragma unroll
    for (int j = 0; j < 13; ++j) acc[j] = (f32x4){0.f, 0.f, 0.f, 0.f};
    float z2p0 = 0.f, z2p1 = 0.f;
    {
        float4 a0 = *(const float4*)(zp0);
        float4 a1 = *(const float4*)(zp0 + 4);
        z2p0 += sq8(a0, a1);
        *(bf16x8*)&Zt[0][srow][scol] = pack8(a0, a1);
        if (r1st) {
            float4 b0 = make_float4(0.f,0.f,0.f,0.f), b1 = b0;
            if (r1v) { b0 = *(const float4*)(zp1); b1 = *(const float4*)(zp1 + 4); }
            z2p1 += sq8(b0, b1);
            *(bf16x8*)&Zt[0][row1][scol] = pack8(b0, b1);
        }
    }
    const int arow = s * 112 + (wid << 4) + (lane & 15);
    const int koff = (lane >> 4) << 3;
    int cur = 0;
#pragma unroll 1
    for (int ks = 0; ks < NKS; ++ks) {
        __syncthreads();
        const bool more = (ks + 1) < NKS;
        float4 a0, a1, b0, b1;
        a0 = a1 = b0 = b1 = make_float4(0.f,0.f,0.f,0.f);
        if (more) {
            const float* p0 = zp0 + (ks + 1) * BK;
            a0 = *(const float4*)(p0); a1 = *(const float4*)(p0 + 4);
            if (r1v) {
                const float* p1 = zp1 + (ks + 1) * BK;
                b0 = *(const float4*)(p1); b1 = *(const float4*)(p1 + 4);
            }
        }
        if (wid < nmf) {
            bf16x8 af = *(const bf16x8*)&Zt[cur][arow][koff];
#pragma unroll
            for (int j = 0; j < 13; ++j) {
                bf16x8 bfr = *(const bf16x8*)&Zt[cur][(j << 4) + (lane & 15)][koff];
                acc[j] = __builtin_amdgcn_mfma_f32_16x16x32_bf16(af, bfr, acc[j], 0, 0, 0);
            }
        }
        if (more) {
            z2p0 += sq8(a0, a1);
            *(bf16x8*)&Zt[cur ^ 1][srow][scol] = pack8(a0, a1);
            if (r1st) {
                z2p1 += sq8(b0, b1);
                *(bf16x8*)&Zt[cur ^ 1][row1][scol] = pack8(b0, b1);
            }
        }
        cur ^= 1;
    }
    float zz0 = z2p0 + __shfl_xor(z2p0, 1); zz0 += __shfl_xor(zz0, 2);
    float zz1 = z2p1 + __shfl_xor(z2p1, 1); zz1 += __shfl_xor(zz1, 2);
    if ((tid & 3) == 0) {
        z2s[srow] = zz0;
        if (r1st) z2s[row1] = r1v ? zz1 : 0.f;
    }
    __syncthreads();

    const float4 sg = *(const float4*)sigma;
    const float c0 = 0.5f / (sg.x * sg.x);
    const float c1 = 0.5f / (sg.y * sg.y);
    const float c2 = 0.5f / (sg.z * sg.z);
    const float c3 = 0.5f / (sg.w * sg.w);
    const int l15 = lane & 15;
    const int lq  = lane >> 4;
    float lsum = 0.f;
    if (wid < nmf) {
        int trow[4]; float z2t[4]; size_t tbase[4];
#pragma unroll
        for (int r = 0; r < 4; ++r) {
            const int t = s * 112 + (wid << 4) + (lq << 2) + r;
            trow[r] = t;
            z2t[r]  = (t < TT) ? z2s[t] : 0.f;
            tbase[r] = ((size_t)b * TT + (t < TT ? t : 0)) * TT;
        }
        const float4* gtp = (const float4*)gt;
#pragma unroll
        for (int j = 0; j < 13; ++j) {
            const int  u  = (j << 4) + l15;
            const bool uv = u < TT;
            const float z2u = uv ? z2s[u] : 0.f;
            float4 dv[4];
#pragma unroll
            for (int r = 0; r < 4; ++r) {
                const bool v = uv && (trow[r] < TT);
                dv[r] = v ? gtp[tbase[r] + u] : make_float4(0.f,0.f,0.f,0.f);
            }
#pragma unroll
            for (int r = 0; r < 4; ++r) {
                const bool v = uv && (trow[r] < TT);
                if (v) {
                    const float sS = dv[r].x*dv[r].x*c0 + dv[r].y*dv[r].y*c1
                                   + dv[r].z*dv[r].z*c2 + dv[r].w*dv[r].w*c3;
                    lsum += __expf(-sS) * (z2t[r] + z2u - 2.f * acc[j][r]);
                }
            }
        }
    }
#pragma unroll
    for (int off = 32; off > 0; off >>= 1) lsum += __shfl_xor(lsum, off);
    if (lane == 0) red[wid] = lsum;
    __syncthreads();
    if (tid == 0) {
        float t = 0.f;
#pragma unroll
        for (int w = 0; w < 8; ++w) t += red[w];
        atomicAdd(out, t * (1.0f / ((float)NB * (float)TT * (float)TT)));
    }
}

// ---------------- launch ----------------

extern "C" void kernel_launch(void* const* d_in, const int* in_sizes, int n_in,
                              void* d_out, int out_size, void* d_ws, size_t ws_size,
                              hipStream_t stream) {
    const float* z     = (const float*)d_in[0];
    const float* gt    = (const float*)d_in[1];
    const float* sigma = (const float*)d_in[2];
    float* out = (float*)d_out;

    const size_t G_elems  = (size_t)NB * TTT;
    const size_t z2_elems = (size_t)NB * TT;
    const size_t need = (G_elems + z2_elems + BGRID) * sizeof(float);   // ~39.6 MB

    if (ws_size >= need) {
        float* G        = (float*)d_ws;
        float* z2g      = G + G_elems;
        float* partials = z2g + z2_elems;
        gram_k <<<dim3(512),  dim3(512), 0, stream>>>(z, G, z2g);
        loss_k <<<dim3(BGRID), dim3(BTH), 0, stream>>>(
            (const float4*)gt, G, z2g, sigma, partials);
        final_k<<<dim3(1),    dim3(256), 0, stream>>>(partials, out);
    } else {
        hipMemsetAsync(out, 0, sizeof(float), stream);
        patch_loss_fused2<<<dim3(512), dim3(NTH), 0, stream>>>(z, gt, sigma, out);
    }
}